// Round 3
// baseline (321.060 us; speedup 1.0000x reference)
//
#include <hip/hip_runtime.h>

#define TT 1024
#define LL 64
#define LOG2E 1.44269504088896340736f
#define LN2   0.69314718055994530942f
#define SHIFT 6.0f

#if __has_builtin(__builtin_amdgcn_fdot2) && __has_builtin(__builtin_amdgcn_cvt_pkrtz)
#define USE_DOT2 1
typedef __fp16 h2 __attribute__((ext_vector_type(2)));
__device__ __forceinline__ h2 int_as_h2(int x) { union { int i; h2 h; } u; u.i = x; return u.h; }
__device__ __forceinline__ int h2_as_int(h2 x) { union { int i; h2 h; } u; u.h = x; return u.i; }
#endif

__device__ __forceinline__ float rlf(float v, int lane) {
    return __int_as_float(__builtin_amdgcn_readlane(__float_as_int(v), lane));
}

// One wave (64 threads) per batch element. Lane j owns CRF state j.
// beta = alpha * log2(e). Per step:
//   p_i = exp2(beta_i - beta_0 - SHIFT)          (m ~ alpha[0]; spread < ~16 in log2)
//   s_j = sum_i p_i * E[i][j],  E = exp(trans)    (32x v_dot2_f32_f16 on packed pairs)
//   beta_j = beta_0 + SHIFT + log2(s_j) + logit[t][j]*LOG2E
// No barriers, no LDS. Logits prefetched 4 rows deep in named registers.

#ifdef USE_DOT2
#define BODY(LGT) { \
    float b0 = __builtin_amdgcn_readfirstlane(beta); \
    float bn = __shfl_xor(beta, 1, 64); \
    float p  = __builtin_amdgcn_exp2f(beta - b0 - SHIFT); \
    float pn = __builtin_amdgcn_exp2f(bn  - b0 - SHIFT); \
    h2 pk = __builtin_amdgcn_cvt_pkrtz(p, pn); \
    int pki = h2_as_int(pk); \
    float a_[4] = {0.f, 0.f, 0.f, 0.f}; \
    _Pragma("unroll") \
    for (int k = 0; k < 32; ++k) { \
        int q_ = __builtin_amdgcn_readlane(pki, 2 * k); \
        a_[k & 3] = __builtin_amdgcn_fdot2(int_as_h2(q_), e2[k], a_[k & 3], false); \
    } \
    float s_ = (a_[0] + a_[1]) + (a_[2] + a_[3]); \
    beta = fmaf(LGT, LOG2E, b0 + SHIFT + __builtin_amdgcn_logf(s_)); \
}
#else
#define BODY(LGT) { \
    float b0 = __builtin_amdgcn_readfirstlane(beta); \
    float p  = __builtin_amdgcn_exp2f(beta - b0 - SHIFT); \
    float a_[4] = {0.f, 0.f, 0.f, 0.f}; \
    _Pragma("unroll") \
    for (int k = 0; k < 64; ++k) { \
        a_[k & 3] = fmaf(rlf(p, k), ef[k], a_[k & 3]); \
    } \
    float s_ = (a_[0] + a_[1]) + (a_[2] + a_[3]); \
    beta = fmaf(LGT, LOG2E, b0 + SHIFT + __builtin_amdgcn_logf(s_)); \
}
#endif

#define STEP_P(F, NR) do { \
    float lgt_ = F; \
    int r_ = (NR); \
    F = lg[(size_t)((r_ < TT) ? r_ : (TT - 1)) * LL + j]; \
    BODY(lgt_); \
} while (0)

#define STEP_T(F) do { float lgt_ = F; BODY(lgt_); } while (0)

__global__ __launch_bounds__(64) void crf_fwd_kernel(
    const float* __restrict__ logits,    // [B][T][L]
    const int*   __restrict__ labels,    // [B][T]
    const int*   __restrict__ seq_lens,  // [B]
    const float* __restrict__ trans,     // [L][L]
    float*       __restrict__ nll)       // [B]
{
    const int b = blockIdx.x;
    const int j = threadIdx.x;            // lane == state
    const int slen = seq_lens[b];
    const float* lg  = logits + (size_t)b * TT * LL;
    const int*   lab = labels + b * TT;

    // ---- Phase A: path score (unary + binary), masked by seq_len ----
    float sc = 0.f;
    for (int t = j; t < slen; t += 64) {
        int l1 = lab[t];
        sc += lg[(size_t)t * LL + l1];
        if (t >= 1) sc += trans[lab[t - 1] * LL + l1];
    }
    #pragma unroll
    for (int off = 32; off; off >>= 1) sc += __shfl_xor(sc, off, 64);
    // every lane now holds the full path score

    // ---- E = exp(trans) column j, packed along i ----
#ifdef USE_DOT2
    h2 e2[32];
    #pragma unroll
    for (int k = 0; k < 32; ++k) {
        float ea = __builtin_amdgcn_exp2f(trans[(2 * k)     * LL + j] * LOG2E);
        float eb = __builtin_amdgcn_exp2f(trans[(2 * k + 1) * LL + j] * LOG2E);
        e2[k] = __builtin_amdgcn_cvt_pkrtz(ea, eb);
    }
#else
    float ef[64];
    #pragma unroll
    for (int k = 0; k < 64; ++k)
        ef[k] = __builtin_amdgcn_exp2f(trans[k * LL + j] * LOG2E);
#endif

    // ---- Phase B: forward recurrence in log2 domain ----
    float beta = lg[j] * LOG2E;          // t = 0
    // prefetch rows 1..4 (clamped; T >= 5 always here)
    float f0 = lg[(size_t)1 * LL + j];
    float f1 = lg[(size_t)2 * LL + j];
    float f2 = lg[(size_t)3 * LL + j];
    float f3 = lg[(size_t)((4 < TT) ? 4 : TT - 1) * LL + j];

    int t = 1;
    for (; t + 4 <= slen; t += 4) {
        STEP_P(f0, t + 4);
        STEP_P(f1, t + 5);
        STEP_P(f2, t + 6);
        STEP_P(f3, t + 7);
    }
    for (; t < slen; ++t) {
        STEP_T(f0);
        f0 = f1; f1 = f2; f2 = f3;
    }

    // ---- Phase C: log_norm = logsumexp(alpha) = (max beta + log2 sum) * ln2 ----
    float mm = beta;
    #pragma unroll
    for (int off = 32; off; off >>= 1) mm = fmaxf(mm, __shfl_xor(mm, off, 64));
    float ex = __builtin_amdgcn_exp2f(beta - mm);
    #pragma unroll
    for (int off = 32; off; off >>= 1) ex += __shfl_xor(ex, off, 64);

    if (j == 0) {
        float log_norm = (mm + __builtin_amdgcn_logf(ex)) * LN2;
        nll[b] = log_norm - sc;
    }
}

__global__ __launch_bounds__(256) void reduce_kernel(
    const float* __restrict__ nll, float* __restrict__ out)
{
    int tid = threadIdx.x;
    float v = nll[tid];
    #pragma unroll
    for (int off = 32; off; off >>= 1) v += __shfl_xor(v, off, 64);
    __shared__ float r[4];
    if ((tid & 63) == 0) r[tid >> 6] = v;
    __syncthreads();
    if (tid == 0) out[0] = (r[0] + r[1]) + (r[2] + r[3]);
}

extern "C" void kernel_launch(void* const* d_in, const int* in_sizes, int n_in,
                              void* d_out, int out_size, void* d_ws, size_t ws_size,
                              hipStream_t stream) {
    const float* logits   = (const float*)d_in[0];
    const int*   labels   = (const int*)d_in[1];
    const int*   seq_lens = (const int*)d_in[2];
    const float* trans    = (const float*)d_in[3];
    float* nll = (float*)d_ws;   // 256 floats of scratch

    crf_fwd_kernel<<<256, 64, 0, stream>>>(logits, labels, seq_lens, trans, nll);
    reduce_kernel<<<1, 256, 0, stream>>>(nll, (float*)d_out);
}

// Round 4
// 299.860 us; speedup vs baseline: 1.0707x; 1.0707x over previous
//
#include <hip/hip_runtime.h>

#define TT 1024
#define LL 64
#define LOG2E 1.44269504088896340736f
#define LN2   0.69314718055994530942f

#if __has_builtin(__builtin_amdgcn_fdot2) && __has_builtin(__builtin_amdgcn_cvt_pkrtz)
#define USE_DOT2 1
typedef __fp16 half2v __attribute__((ext_vector_type(2)));
__device__ __forceinline__ half2v int_as_h2(int x) { union { int i; half2v h; } u; u.i = x; return u.h; }
__device__ __forceinline__ int h2_as_int(half2v x) { union { int i; half2v h; } u; u.h = x; return u.i; }
#endif

__device__ __forceinline__ float rlf(float v, int lane) {
    return __int_as_float(__builtin_amdgcn_readlane(__float_as_int(v), lane));
}

// One wave per batch element. Real-space recurrence:
//   v_j = (sum_i u_i * E_ij) * g_j,   E = exp(trans), g_j = exp(logit[t][j])
//   u'_j = v_j * 2^-e,  e = exponent(v_0)   (exact pow2 renorm, C += e)
// alpha_j = (log2(u_j) + C) * ln2.  No exp/log/shfl on the serial chain:
// g is precomputed off-chain, renorm is readfirstlane + SALU + mul.
// f16-pair state: lane k holds (u_2k, u_2k+1) packed; matvec = 32 readlane
// + 64 v_dot2_f32_f16 with E columns resident in VGPRs.

__global__ __launch_bounds__(64) void crf_fwd_kernel(
    const float* __restrict__ logits,    // [B][T][L]
    const int*   __restrict__ labels,    // [B][T]
    const int*   __restrict__ seq_lens,  // [B]
    const float* __restrict__ trans,     // [L][L]
    float*       __restrict__ nll)       // [B]
{
    const int b    = blockIdx.x;
    const int lane = threadIdx.x;
    const int k    = lane & 31;          // pair index: outputs j1=2k, j2=2k+1
    const int slen = seq_lens[b];
    const float* lg  = logits + (size_t)b * TT * LL;
    const int*   lab = labels + b * TT;

    // ---- Phase A: path score (unary + binary), masked by seq_len ----
    float sc = 0.f;
    for (int t = lane; t < slen; t += 64) {
        int l1 = lab[t];
        sc += lg[(size_t)t * LL + l1];
        if (t >= 1) sc += trans[lab[t - 1] * LL + l1];
    }
    #pragma unroll
    for (int off = 32; off; off >>= 1) sc += __shfl_xor(sc, off, 64);

    const int j1 = 2 * k, j2 = 2 * k + 1;

#ifdef USE_DOT2
    // E pairs along i for this lane's two output columns (f16 RTN via casts)
    int ea[32], eb[32];
    #pragma unroll
    for (int i2 = 0; i2 < 32; ++i2) {
        half2v pa, pb;
        pa[0] = (__fp16)__builtin_amdgcn_exp2f(trans[(2 * i2)     * LL + j1] * LOG2E);
        pa[1] = (__fp16)__builtin_amdgcn_exp2f(trans[(2 * i2 + 1) * LL + j1] * LOG2E);
        pb[0] = (__fp16)__builtin_amdgcn_exp2f(trans[(2 * i2)     * LL + j2] * LOG2E);
        pb[1] = (__fp16)__builtin_amdgcn_exp2f(trans[(2 * i2 + 1) * LL + j2] * LOG2E);
        ea[i2] = h2_as_int(pa);
        eb[i2] = h2_as_int(pb);
    }
#else
    float ef[64];   // fallback: lane j owns column j
    #pragma unroll
    for (int i = 0; i < 64; ++i)
        ef[i] = __builtin_amdgcn_exp2f(trans[i * LL + lane] * LOG2E);
#endif

    // rolling raw-logit pairs for rows t+1..t+4 (this lane's columns j1,j2)
    const float* col = lg + j1;
    #define LDROW(r) (*(const float2*)(col + (size_t)(r) * LL))

    float2 r0 = LDROW(0);
    float2 rA = LDROW(1 < TT ? 1 : TT - 1);
    float2 rB = LDROW(2 < TT ? 2 : TT - 1);
    float2 rC = LDROW(3 < TT ? 3 : TT - 1);
    float2 rD = LDROW(4 < TT ? 4 : TT - 1);

    float G1 = __builtin_amdgcn_exp2f(r0.x * LOG2E);
    float G2 = __builtin_amdgcn_exp2f(r0.y * LOG2E);

    int C = 0;
#ifdef USE_DOT2
    int upk;
#else
    float u;
#endif

    // ---- renorm helper applied to (v1,v2): scale so that v_0 in [1,2) ----
#ifdef USE_DOT2
#define RENORM_PACK(V1, V2) { \
    int ebits = (__builtin_amdgcn_readfirstlane(__float_as_int(V1)) >> 23) & 0xFF; \
    C += ebits - 127; \
    float scl = __int_as_float((254 - ebits) << 23); \
    upk = h2_as_int(__builtin_amdgcn_cvt_pkrtz((V1) * scl, (V2) * scl)); \
}
#else
#define RENORM_PACK(V1, V2) { \
    int ebits = (__builtin_amdgcn_readfirstlane(__float_as_int(V1)) >> 23) & 0xFF; \
    C += ebits - 127; \
    float scl = __int_as_float((254 - ebits) << 23); \
    u = (V1) * scl; \
}
#endif

    // t = 0: u = normalized exp(logit0)
    {
        float v1 = G1, v2 = G2;
#ifndef USE_DOT2
        v1 = __builtin_amdgcn_exp2f(lg[lane] * LOG2E);  v2 = v1;
#endif
        RENORM_PACK(v1, v2);
    }
    G1 = __builtin_amdgcn_exp2f(rA.x * LOG2E);
    G2 = __builtin_amdgcn_exp2f(rA.y * LOG2E);
#ifndef USE_DOT2
    float Gs = __builtin_amdgcn_exp2f(lg[(1 < TT ? 1 : TT - 1) * LL + lane] * LOG2E);
#endif

    for (int t = 1; t < slen; ++t) {
#ifdef USE_DOT2
        float a1 = 0.f, a2 = 0.f, b1 = 0.f, b2 = 0.f;
        #pragma unroll
        for (int i2 = 0; i2 < 32; i2 += 2) {
            int q0 = __builtin_amdgcn_readlane(upk, i2);
            int q1 = __builtin_amdgcn_readlane(upk, i2 + 1);
            a1 = __builtin_amdgcn_fdot2(int_as_h2(q0), int_as_h2(ea[i2]),     a1, false);
            b1 = __builtin_amdgcn_fdot2(int_as_h2(q0), int_as_h2(eb[i2]),     b1, false);
            a2 = __builtin_amdgcn_fdot2(int_as_h2(q1), int_as_h2(ea[i2 + 1]), a2, false);
            b2 = __builtin_amdgcn_fdot2(int_as_h2(q1), int_as_h2(eb[i2 + 1]), b2, false);
        }
        float v1 = (a1 + a2) * G1;
        float v2 = (b1 + b2) * G2;
        RENORM_PACK(v1, v2);
        // prepare g for step t+1 (off critical path)
        G1 = __builtin_amdgcn_exp2f(rB.x * LOG2E);
        G2 = __builtin_amdgcn_exp2f(rB.y * LOG2E);
#else
        float s0 = 0.f, s1 = 0.f, s2 = 0.f, s3 = 0.f;
        #pragma unroll
        for (int i = 0; i < 64; i += 4) {
            s0 = fmaf(rlf(u, i),     ef[i],     s0);
            s1 = fmaf(rlf(u, i + 1), ef[i + 1], s1);
            s2 = fmaf(rlf(u, i + 2), ef[i + 2], s2);
            s3 = fmaf(rlf(u, i + 3), ef[i + 3], s3);
        }
        float v1 = ((s0 + s1) + (s2 + s3)) * Gs;
        RENORM_PACK(v1, v1);
        int nr = t + 1; nr = nr < TT ? nr : TT - 1;
        Gs = __builtin_amdgcn_exp2f(lg[(size_t)nr * LL + lane] * LOG2E);
#endif
        rA = rB; rB = rC; rC = rD;
        int nr4 = t + 4; nr4 = nr4 < TT ? nr4 : TT - 1;
        rD = LDROW(nr4);
    }

    // ---- Final: log_norm = (C + log2(sum u) - dup) * ln2 ----
#ifdef USE_DOT2
    half2v uh = int_as_h2(upk);
    float usum = (float)uh[0] + (float)uh[1];
    #pragma unroll
    for (int off = 32; off; off >>= 1) usum += __shfl_xor(usum, off, 64);
    // lanes 32..63 duplicate lanes 0..31 -> sum is 2x: subtract 1 in log2
    float log_norm = ((float)C + __builtin_amdgcn_logf(usum) - 1.0f) * LN2;
#else
    float usum = u;
    #pragma unroll
    for (int off = 32; off; off >>= 1) usum += __shfl_xor(usum, off, 64);
    float log_norm = ((float)C + __builtin_amdgcn_logf(usum)) * LN2;
#endif

    if (lane == 0) nll[b] = log_norm - sc;
}

__global__ __launch_bounds__(256) void reduce_kernel(
    const float* __restrict__ nll, float* __restrict__ out)
{
    int tid = threadIdx.x;
    float v = nll[tid];
    #pragma unroll
    for (int off = 32; off; off >>= 1) v += __shfl_xor(v, off, 64);
    __shared__ float r[4];
    if ((tid & 63) == 0) r[tid >> 6] = v;
    __syncthreads();
    if (tid == 0) out[0] = (r[0] + r[1]) + (r[2] + r[3]);
}

extern "C" void kernel_launch(void* const* d_in, const int* in_sizes, int n_in,
                              void* d_out, int out_size, void* d_ws, size_t ws_size,
                              hipStream_t stream) {
    const float* logits   = (const float*)d_in[0];
    const int*   labels   = (const int*)d_in[1];
    const int*   seq_lens = (const int*)d_in[2];
    const float* trans    = (const float*)d_in[3];
    float* nll = (float*)d_ws;   // 256 floats of scratch

    crf_fwd_kernel<<<256, 64, 0, stream>>>(logits, labels, seq_lens, trans, nll);
    reduce_kernel<<<1, 256, 0, stream>>>(nll, (float*)d_out);
}